// Round 3
// baseline (62.926 us; speedup 1.0000x reference)
//
#include <hip/hip_runtime.h>
#include <hip/hip_bf16.h>

// SpiralConv: out[n][o] = sum_{s,c} x[idx[n][s]][c] * W[o][s*32+c] + b[o]
// N=163842, SEQ=9, IN_CH=32, OUT_CH=64.
// bf16 MFMA gather-GEMM, round 3:
//  - M=16 nodes/wave (full 9-gather prefetch in ~80 VGPR -> 4 waves/SIMD)
//  - nontemporal stores for out + nt loads for read-once streams (x, idx)
//    so the 42MB output stream stops evicting the 10.5MB xb gather set
//    from the per-XCD L2s.

constexpr int NN   = 163842;
constexpr int SEQ  = 9;
constexpr int INC  = 32;
constexpr int OUTC = 64;
constexpr int FAN  = SEQ * INC;  // 288

using s8    = __attribute__((ext_vector_type(8))) short;   // 8 bf16 = 4 VGPRs
using f32x4 = __attribute__((ext_vector_type(4))) float;

__device__ __forceinline__ unsigned f2bf(float f) {
    union { float f; unsigned u; } c; c.f = f;
    unsigned u = c.u;
    u += 0x7fffu + ((u >> 16) & 1u);   // RNE
    return (u >> 16) & 0xffffu;
}

// Convert x [NN*INC] and W [OUTC*FAN] fp32 -> bf16 into workspace.
__global__ __launch_bounds__(256) void convert_bf16_kernel(
    const float* __restrict__ x, const float* __restrict__ W,
    unsigned short* __restrict__ xb, unsigned short* __restrict__ wb)
{
    const int xq = NN * INC / 4;
    const int wq = OUTC * FAN / 4;
    int i = blockIdx.x * blockDim.x + threadIdx.x;
    if (i < xq) {
        // x is read exactly once -> nontemporal, keep L2 for xb later
        f32x4 v = __builtin_nontemporal_load(reinterpret_cast<const f32x4*>(x) + i);
        unsigned lo = f2bf(v[0]) | (f2bf(v[1]) << 16);
        unsigned hi = f2bf(v[2]) | (f2bf(v[3]) << 16);
        reinterpret_cast<uint2*>(xb)[i] = make_uint2(lo, hi);
    } else if (i < xq + wq) {
        int j = i - xq;
        f32x4 v = *(reinterpret_cast<const f32x4*>(W) + j);
        unsigned lo = f2bf(v[0]) | (f2bf(v[1]) << 16);
        unsigned hi = f2bf(v[2]) | (f2bf(v[3]) << 16);
        reinterpret_cast<uint2*>(wb)[j] = make_uint2(lo, hi);
    }
}

// Gather-GEMM. Block = 256 = 4 waves; wave = 16 nodes x 64 outs.
// A-frag = W row (o = f*16+lc), B-frag = gathered x row (node = base+lc),
// both 16B contiguous loads. D[row=o][col=node]: lane reg r ->
// o = f*16 + (lane>>4)*4 + r, node = base + (lane&15) -> float4 store.
__global__ __launch_bounds__(256) void spiral_gemm_kernel(
    const int* __restrict__ idx,              // [NN][SEQ] int32
    const unsigned short* __restrict__ xb,    // [NN][INC] bf16
    const unsigned short* __restrict__ wb,    // [OUTC][FAN] bf16
    const float* __restrict__ bias,           // [OUTC]
    float* __restrict__ out)                  // [NN][OUTC]
{
    const int lane = threadIdx.x & 63;
    const int wid  = threadIdx.x >> 6;
    const int lc   = lane & 15;
    const int lk   = lane >> 4;
    const int kb   = lk * 8;

    const int nodeBase = blockIdx.x * 64 + wid * 16;
    const int r = min(nodeBase + lc, NN - 1);   // clamp tail; never stored
    const int* ip = idx + (size_t)r * SEQ;

    // ---- Prefetch: 9 indices (read-once -> nt), then 9 row-gathers ----
    int nidx[SEQ];
    #pragma unroll
    for (int s = 0; s < SEQ; ++s)
        nidx[s] = __builtin_nontemporal_load(ip + s);

    s8 xf[SEQ];
    #pragma unroll
    for (int s = 0; s < SEQ; ++s)
        xf[s] = *reinterpret_cast<const s8*>(xb + (size_t)nidx[s] * INC + kb);

    // ---- MFMA: W frags stream from L1 ----
    f32x4 acc[4] = {};
    #pragma unroll
    for (int s = 0; s < SEQ; ++s) {
        #pragma unroll
        for (int f = 0; f < 4; ++f) {
            s8 wf = *reinterpret_cast<const s8*>(wb + (f * 16 + lc) * FAN + s * 32 + kb);
            acc[f] = __builtin_amdgcn_mfma_f32_16x16x32_bf16(wf, xf[s], acc[f], 0, 0, 0);
        }
    }

    // ---- Epilogue: bias + nontemporal float4 stores ----
    const int node = nodeBase + lc;
    if (node < NN) {
        #pragma unroll
        for (int f = 0; f < 4; ++f) {
            f32x4 b4 = *reinterpret_cast<const f32x4*>(bias + f * 16 + lk * 4);
            f32x4 v = acc[f] + b4;
            __builtin_nontemporal_store(v,
                reinterpret_cast<f32x4*>(out + (size_t)node * OUTC + f * 16 + lk * 4));
        }
    }
}

extern "C" void kernel_launch(void* const* d_in, const int* in_sizes, int n_in,
                              void* d_out, int out_size, void* d_ws, size_t ws_size,
                              hipStream_t stream) {
    const float* x    = (const float*)d_in[0];
    const int*   idx  = (const int*)d_in[1];
    const float* W    = (const float*)d_in[2];
    const float* b    = (const float*)d_in[3];
    float*       out  = (float*)d_out;

    unsigned short* xb = (unsigned short*)d_ws;          // NN*INC bf16 = 10.5 MB
    unsigned short* wb = xb + (size_t)NN * INC;          // OUTC*FAN bf16 = 36 KB

    const int totalq = (NN * INC + OUTC * FAN) / 4;
    convert_bf16_kernel<<<(totalq + 255) / 256, 256, 0, stream>>>(x, W, xb, wb);

    const int nblocks = (NN + 63) / 64;                  // 2561
    spiral_gemm_kernel<<<nblocks, 256, 0, stream>>>(idx, xb, wb, b, out);
}

// Round 4
// 48.224 us; speedup vs baseline: 1.3049x; 1.3049x over previous
//
#include <hip/hip_runtime.h>
#include <hip/hip_bf16.h>

// SpiralConv: out[n][o] = sum_{s,c} x[idx[n][s]][c] * W[o][s*32+c] + b[o]
// N=163842, SEQ=9, IN_CH=32, OUT_CH=64.
// Round 4: model = L1/TA services ~1 line/4cy; minimize cache-lines touched
// per node. W fragments (36 loads/wave, 16 lines each) move to LDS
// (separate pipe); idx distributed via LDS; gathers+stores stay on L1 path.
// NT hints reverted (round-3 regression).

constexpr int NN   = 163842;
constexpr int SEQ  = 9;
constexpr int INC  = 32;
constexpr int OUTC = 64;
constexpr int FAN  = SEQ * INC;          // 288
constexpr int IDX_TOT = NN * SEQ;        // 1,474,578 ints

using s8    = __attribute__((ext_vector_type(8))) short;   // 8 bf16
using f32x4 = __attribute__((ext_vector_type(4))) float;

__device__ __forceinline__ unsigned f2bf(float f) {
    union { float f; unsigned u; } c; c.f = f;
    unsigned u = c.u;
    u += 0x7fffu + ((u >> 16) & 1u);   // RNE
    return (u >> 16) & 0xffffu;
}

// Convert x [NN*INC] and W [OUTC*FAN] fp32 -> bf16 into workspace (plain loads).
__global__ __launch_bounds__(256) void convert_bf16_kernel(
    const float* __restrict__ x, const float* __restrict__ W,
    unsigned short* __restrict__ xb, unsigned short* __restrict__ wb)
{
    const int xq = NN * INC / 4;
    const int wq = OUTC * FAN / 4;
    int i = blockIdx.x * blockDim.x + threadIdx.x;
    if (i < xq) {
        float4 v = reinterpret_cast<const float4*>(x)[i];
        unsigned lo = f2bf(v.x) | (f2bf(v.y) << 16);
        unsigned hi = f2bf(v.z) | (f2bf(v.w) << 16);
        reinterpret_cast<uint2*>(xb)[i] = make_uint2(lo, hi);
    } else if (i < xq + wq) {
        int j = i - xq;
        float4 v = reinterpret_cast<const float4*>(W)[j];
        unsigned lo = f2bf(v.x) | (f2bf(v.y) << 16);
        unsigned hi = f2bf(v.z) | (f2bf(v.w) << 16);
        reinterpret_cast<uint2*>(wb)[j] = make_uint2(lo, hi);
    }
}

// Block = 256 thr = 4 waves; wave = 32 nodes x 64 outs (2 m-frags x 4 f-frags).
// W lives in LDS (XOR-swizzled rows, stride 576B); idx staged via LDS.
__global__ __launch_bounds__(256) void spiral_gemm_kernel(
    const int* __restrict__ idx,              // [NN][SEQ] int32
    const unsigned short* __restrict__ xb,    // [NN][INC] bf16
    const unsigned short* __restrict__ wb,    // [OUTC][FAN] bf16
    const float* __restrict__ bias,           // [OUTC]
    float* __restrict__ out)                  // [NN][OUTC]
{
    __shared__ unsigned char wlds[64 * 576];  // 36,864 B, byte ^= (row&7)<<4
    __shared__ int ilds[128 * SEQ];           // 4,608 B

    const int tid  = threadIdx.x;
    const int lane = tid & 63;
    const int wid  = tid >> 6;
    const int lc   = lane & 15;
    const int lk   = lane >> 4;
    const int kb   = lk * 8;

    const int blockNode = blockIdx.x * 128;

    // ---- A) stage idx for the block's 128 nodes (coalesced, clamped) ----
    {
        const int base = blockNode * SEQ;
        #pragma unroll
        for (int k = 0; k < 5; ++k) {
            int i = tid + k * 256;
            if (i < 128 * SEQ) {
                int g = base + i;
                if (g > IDX_TOT - 1) g = IDX_TOT - 1;   // tail-block safety
                ilds[i] = idx[g];
            }
        }
    }
    __syncthreads();

    // ---- B) read this wave's 18 indices (LDS broadcast), issue gathers ----
    const int nl0 = wid * 32 + lc;
    const int nl1 = nl0 + 16;
    int n0[SEQ], n1[SEQ];
    #pragma unroll
    for (int s = 0; s < SEQ; ++s) {
        unsigned a = (unsigned)ilds[nl0 * SEQ + s];
        unsigned b = (unsigned)ilds[nl1 * SEQ + s];
        n0[s] = (a >= (unsigned)NN) ? 0 : (int)a;   // garbage-safe (tail)
        n1[s] = (b >= (unsigned)NN) ? 0 : (int)b;
    }
    s8 xf0[SEQ], xf1[SEQ];
    #pragma unroll
    for (int s = 0; s < SEQ; ++s) {
        xf0[s] = *reinterpret_cast<const s8*>(xb + (size_t)n0[s] * INC + kb);
        xf1[s] = *reinterpret_cast<const s8*>(xb + (size_t)n1[s] * INC + kb);
    }

    // ---- C) stage W -> LDS (overlaps gather latency) ----
    {
        const uint4* w4 = reinterpret_cast<const uint4*>(wb);  // 2304 uint4
        #pragma unroll
        for (int k = 0; k < 9; ++k) {
            int i4  = tid + k * 256;
            int row = i4 / 36;            // W row (o), 36 x 16B per row
            int c16 = i4 % 36;
            unsigned boff = (unsigned)(row * 576 + c16 * 16) ^ ((unsigned)(row & 7) << 4);
            *reinterpret_cast<uint4*>(&wlds[boff]) = w4[i4];
        }
    }
    __syncthreads();

    // ---- D) MFMA: W frags from LDS, gathers from registers ----
    f32x4 acc[2][4] = {};
    #pragma unroll
    for (int s = 0; s < SEQ; ++s) {
        #pragma unroll
        for (int f = 0; f < 4; ++f) {
            const int row = f * 16 + lc;
            unsigned boff = (unsigned)(row * 576 + s * 64 + lk * 16) ^ ((unsigned)(lc & 7) << 4);
            s8 wf = *reinterpret_cast<const s8*>(&wlds[boff]);
            acc[0][f] = __builtin_amdgcn_mfma_f32_16x16x32_bf16(wf, xf0[s], acc[0][f], 0, 0, 0);
            acc[1][f] = __builtin_amdgcn_mfma_f32_16x16x32_bf16(wf, xf1[s], acc[1][f], 0, 0, 0);
        }
    }

    // ---- E) epilogue: bias + float4 stores ----
    #pragma unroll
    for (int f = 0; f < 4; ++f) {
        const f32x4 b4 = *reinterpret_cast<const f32x4*>(bias + f * 16 + lk * 4);
        #pragma unroll
        for (int m = 0; m < 2; ++m) {
            const int node = blockNode + wid * 32 + m * 16 + lc;
            if (node < NN) {
                f32x4 v = acc[m][f] + b4;
                *reinterpret_cast<f32x4*>(out + (size_t)node * OUTC + f * 16 + lk * 4) = v;
            }
        }
    }
}

extern "C" void kernel_launch(void* const* d_in, const int* in_sizes, int n_in,
                              void* d_out, int out_size, void* d_ws, size_t ws_size,
                              hipStream_t stream) {
    const float* x    = (const float*)d_in[0];
    const int*   idx  = (const int*)d_in[1];
    const float* W    = (const float*)d_in[2];
    const float* b    = (const float*)d_in[3];
    float*       out  = (float*)d_out;

    unsigned short* xb = (unsigned short*)d_ws;          // NN*INC bf16 = 10.5 MB
    unsigned short* wb = xb + (size_t)NN * INC;          // OUTC*FAN bf16 = 36 KB (16B-aligned)

    const int totalq = (NN * INC + OUTC * FAN) / 4;
    convert_bf16_kernel<<<(totalq + 255) / 256, 256, 0, stream>>>(x, W, xb, wb);

    const int nblocks = (NN + 127) / 128;                // 1281
    spiral_gemm_kernel<<<nblocks, 256, 0, stream>>>(idx, xb, wb, b, out);
}